// Round 4
// baseline (3697.980 us; speedup 1.0000x reference)
//
#include <hip/hip_runtime.h>

#define NN 50000
#define DD 128
#define EE 500000

// ---------------- degree ----------------
__global__ __launch_bounds__(256) void degree_kernel(const int* __restrict__ dst0,
                                                     const int* __restrict__ dst1,
                                                     float* __restrict__ deg0,
                                                     float* __restrict__ deg1) {
    int i = blockIdx.x * 256 + threadIdx.x;
    if (i < EE) {
        atomicAdd(&deg0[dst0[i]], 1.0f);
        atomicAdd(&deg1[dst1[i]], 1.0f);
    }
}

// in-place: deg -> 1/max(deg,1)
__global__ __launch_bounds__(256) void rdeg_kernel(float* __restrict__ deg0,
                                                   float* __restrict__ deg1) {
    int i = blockIdx.x * 256 + threadIdx.x;
    if (i < NN) {
        deg0[i] = 1.0f / fmaxf(deg0[i], 1.0f);
        deg1[i] = 1.0f / fmaxf(deg1[i], 1.0f);
    }
}

// ---------------- aggregation: sum[dst] += x[src] ----------------
// one thread per (edge, 4 features); E*32 threads = 16M, exactly 62500 blocks
__global__ __launch_bounds__(256) void agg_kernel(const float* __restrict__ x,
                                                  const int* __restrict__ src,
                                                  const int* __restrict__ dst,
                                                  float* __restrict__ sum) {
    int t = blockIdx.x * 256 + threadIdx.x;
    int e = t >> 5;
    int q = (t & 31) << 2;
    int s = src[e];
    int d = dst[e];
    const float4 v = *reinterpret_cast<const float4*>(&x[(size_t)s * DD + q]);
    float* p = &sum[(size_t)d * DD + q];
    atomicAdd(p + 0, v.x);
    atomicAdd(p + 1, v.y);
    atomicAdd(p + 2, v.z);
    atomicAdd(p + 3, v.w);
}

// ---------------- fused mean-combine + dual GEMM + bias (+ReLU) ----------------
// out[n,d] = 2*x[n,:]@Ws[:,d] + (sum0[n,:]*rdeg0[n] + sum1[n,:]*rdeg1[n])@Wn[:,d] + 2*b[d]
// block: 256 threads = 128 cols x 2 row-groups (4 rows each) -> 8 rows/block
// 50000/8 = 6250 blocks exactly.
__global__ __launch_bounds__(256) void gemm_kernel(const float* __restrict__ x,
                                                   const float* __restrict__ sum0,
                                                   const float* __restrict__ sum1,
                                                   const float* __restrict__ rdeg0,
                                                   const float* __restrict__ rdeg1,
                                                   const float* __restrict__ Ws,
                                                   const float* __restrict__ Wn,
                                                   const float* __restrict__ b,
                                                   float* __restrict__ out,
                                                   int relu) {
    __shared__ float x2t[8][DD];  // 2*x rows
    __shared__ float gt[8][DD];   // combined mean rows
    const int tid  = threadIdx.x;
    const int row0 = blockIdx.x * 8;

    // stage 8 rows: each thread handles one float4 chunk (256 chunks total)
    {
        int r  = tid >> 5;
        int c4 = (tid & 31) << 2;
        int n  = row0 + r;
        float4 xv = *reinterpret_cast<const float4*>(&x[(size_t)n * DD + c4]);
        float4 s0 = *reinterpret_cast<const float4*>(&sum0[(size_t)n * DD + c4]);
        float4 s1 = *reinterpret_cast<const float4*>(&sum1[(size_t)n * DD + c4]);
        float r0 = rdeg0[n], r1 = rdeg1[n];
        x2t[r][c4 + 0] = 2.0f * xv.x;
        x2t[r][c4 + 1] = 2.0f * xv.y;
        x2t[r][c4 + 2] = 2.0f * xv.z;
        x2t[r][c4 + 3] = 2.0f * xv.w;
        gt[r][c4 + 0] = s0.x * r0 + s1.x * r1;
        gt[r][c4 + 1] = s0.y * r0 + s1.y * r1;
        gt[r][c4 + 2] = s0.z * r0 + s1.z * r1;
        gt[r][c4 + 3] = s0.w * r0 + s1.w * r1;
    }
    __syncthreads();

    const int d  = tid & 127;
    const int rg = tid >> 7;  // 0..1
    float acc[4] = {0.f, 0.f, 0.f, 0.f};

    for (int k = 0; k < DD; k += 4) {
        float ws[4], wn[4];
#pragma unroll
        for (int kk = 0; kk < 4; ++kk) {
            ws[kk] = Ws[(size_t)(k + kk) * DD + d];
            wn[kk] = Wn[(size_t)(k + kk) * DD + d];
        }
#pragma unroll
        for (int i = 0; i < 4; ++i) {
            const float4 xv = *reinterpret_cast<const float4*>(&x2t[rg * 4 + i][k]);
            const float4 gv = *reinterpret_cast<const float4*>(&gt[rg * 4 + i][k]);
            acc[i] = fmaf(xv.x, ws[0], acc[i]);
            acc[i] = fmaf(xv.y, ws[1], acc[i]);
            acc[i] = fmaf(xv.z, ws[2], acc[i]);
            acc[i] = fmaf(xv.w, ws[3], acc[i]);
            acc[i] = fmaf(gv.x, wn[0], acc[i]);
            acc[i] = fmaf(gv.y, wn[1], acc[i]);
            acc[i] = fmaf(gv.z, wn[2], acc[i]);
            acc[i] = fmaf(gv.w, wn[3], acc[i]);
        }
    }

    const float bb = 2.0f * b[d];
#pragma unroll
    for (int i = 0; i < 4; ++i) {
        int n   = row0 + rg * 4 + i;
        float v = acc[i] + bb;
        if (relu) v = fmaxf(v, 0.0f);
        out[(size_t)n * DD + d] = v;
    }
}

extern "C" void kernel_launch(void* const* d_in, const int* in_sizes, int n_in,
                              void* d_out, int out_size, void* d_ws, size_t ws_size,
                              hipStream_t stream) {
    (void)in_sizes; (void)n_in; (void)out_size; (void)ws_size;

    const float* h    = (const float*)d_in[0];
    const int*   src0 = (const int*)d_in[1];
    const int*   dst0 = (const int*)d_in[2];
    const int*   src1 = (const int*)d_in[3];
    const int*   dst1 = (const int*)d_in[4];
    const float* Ws1  = (const float*)d_in[5];
    const float* Wn1  = (const float*)d_in[6];
    const float* b1   = (const float*)d_in[7];
    const float* Ws2  = (const float*)d_in[8];
    const float* Wn2  = (const float*)d_in[9];
    const float* b2   = (const float*)d_in[10];
    float* out = (float*)d_out;

    const size_t ND = (size_t)NN * DD;
    float* sum0 = (float*)d_ws;          // ND floats
    float* sum1 = sum0 + ND;             // ND floats
    float* h1   = sum1 + ND;             // ND floats
    float* deg0 = h1 + ND;               // N floats (becomes rdeg in-place)
    float* deg1 = deg0 + NN;             // N floats

    const int degBlocks  = (EE + 255) / 256;
    const int rdegBlocks = (NN + 255) / 256;
    const int aggBlocks  = (EE * 32) / 256;  // 62500 exact
    const int gemmBlocks = NN / 8;           // 6250 exact

    // degrees (layer-invariant)
    hipMemsetAsync(deg0, 0, 2 * (size_t)NN * sizeof(float), stream);
    degree_kernel<<<degBlocks, 256, 0, stream>>>(dst0, dst1, deg0, deg1);
    rdeg_kernel<<<rdegBlocks, 256, 0, stream>>>(deg0, deg1);

    // ---- layer 1 ----
    hipMemsetAsync(sum0, 0, 2 * ND * sizeof(float), stream);
    agg_kernel<<<aggBlocks, 256, 0, stream>>>(h, src0, dst0, sum0);
    agg_kernel<<<aggBlocks, 256, 0, stream>>>(h, src1, dst1, sum1);
    gemm_kernel<<<gemmBlocks, 256, 0, stream>>>(h, sum0, sum1, deg0, deg1,
                                                Ws1, Wn1, b1, h1, 1);

    // ---- layer 2 ----
    hipMemsetAsync(sum0, 0, 2 * ND * sizeof(float), stream);
    agg_kernel<<<aggBlocks, 256, 0, stream>>>(h1, src0, dst0, sum0);
    agg_kernel<<<aggBlocks, 256, 0, stream>>>(h1, src1, dst1, sum1);
    gemm_kernel<<<gemmBlocks, 256, 0, stream>>>(h1, sum0, sum1, deg0, deg1,
                                                Ws2, Wn2, b2, out, 0);
}

// Round 9
// 563.233 us; speedup vs baseline: 6.5656x; 6.5656x over previous
//
#include <hip/hip_runtime.h>

#define NN 50000
#define DD 128
#define EE 500000

// ---------------- int degree histogram (both edge types) ----------------
__global__ __launch_bounds__(256) void degi_kernel(const int* __restrict__ dst0,
                                                   const int* __restrict__ dst1,
                                                   int* __restrict__ deg0,
                                                   int* __restrict__ deg1) {
    int i = blockIdx.x * 256 + threadIdx.x;
    if (i < EE) {
        atomicAdd(&deg0[dst0[i]], 1);
        atomicAdd(&deg1[dst1[i]], 1);
    }
}

// ---------------- exclusive scan deg -> row_ptr (one block per edge type) ----------------
__global__ __launch_bounds__(1024) void scan_kernel(const int* __restrict__ deg0,
                                                    const int* __restrict__ deg1,
                                                    int* __restrict__ rp0,
                                                    int* __restrict__ rp1) {
    const int* deg = blockIdx.x ? deg1 : deg0;
    int* rp = blockIdx.x ? rp1 : rp0;
    __shared__ int spart[1024];
    int running = 0;
    for (int base = 0; base < NN; base += 8192) {
        int i0 = base + threadIdx.x * 8;
        int v[8];
        int local = 0;
#pragma unroll
        for (int j = 0; j < 8; ++j) {
            int idx = i0 + j;
            v[j] = (idx < NN) ? deg[idx] : 0;
            local += v[j];
        }
        spart[threadIdx.x] = local;
        __syncthreads();
        for (int off = 1; off < 1024; off <<= 1) {
            int t = (threadIdx.x >= off) ? spart[threadIdx.x - off] : 0;
            __syncthreads();
            spart[threadIdx.x] += t;
            __syncthreads();
        }
        int excl = running + spart[threadIdx.x] - local;
        int total = spart[1023];
#pragma unroll
        for (int j = 0; j < 8; ++j) {
            int idx = i0 + j;
            if (idx < NN) rp[idx] = excl;
            excl += v[j];
        }
        running += total;
        __syncthreads();
    }
    if (threadIdx.x == 0) rp[NN] = running;
}

// ---------------- rdeg = 1/max(deg,1) ----------------
__global__ __launch_bounds__(256) void rdegi_kernel(const int* __restrict__ deg0,
                                                    const int* __restrict__ deg1,
                                                    float* __restrict__ rdeg0,
                                                    float* __restrict__ rdeg1) {
    int i = blockIdx.x * 256 + threadIdx.x;
    if (i < NN) {
        rdeg0[i] = 1.0f / fmaxf((float)deg0[i], 1.0f);
        rdeg1[i] = 1.0f / fmaxf((float)deg1[i], 1.0f);
    }
}

// ---------------- scatter edges into CSR (both edge types) ----------------
__global__ __launch_bounds__(256) void fill_kernel(const int* __restrict__ src0,
                                                   const int* __restrict__ dst0,
                                                   const int* __restrict__ src1,
                                                   const int* __restrict__ dst1,
                                                   const int* __restrict__ rp0,
                                                   int* __restrict__ cur0,
                                                   int* __restrict__ csr0,
                                                   const int* __restrict__ rp1,
                                                   int* __restrict__ cur1,
                                                   int* __restrict__ csr1) {
    int e = blockIdx.x * 256 + threadIdx.x;
    if (e < EE) {
        int d0 = dst0[e];
        int p0 = atomicAdd(&cur0[d0], 1);
        csr0[rp0[d0] + p0] = src0[e];
        int d1 = dst1[e];
        int p1 = atomicAdd(&cur1[d1], 1);
        csr1[rp1[d1] + p1] = src1[e];
    }
}

// ---------------- gather aggregation: gt[n] = mean0[n] + mean1[n] combined ----------------
// one wave per node (64 lanes x float2 = 128 cols = 512B row); 4 nodes/block
__global__ __launch_bounds__(256) void agg_gather_kernel(const float* __restrict__ x,
                                                         const int* __restrict__ rp0,
                                                         const int* __restrict__ csr0,
                                                         const int* __restrict__ rp1,
                                                         const int* __restrict__ csr1,
                                                         const float* __restrict__ rdeg0,
                                                         const float* __restrict__ rdeg1,
                                                         float* __restrict__ gt) {
    int node = blockIdx.x * 4 + (threadIdx.x >> 6);
    int c = (threadIdx.x & 63) * 2;
    float2 a0 = make_float2(0.f, 0.f);
    float2 a1 = make_float2(0.f, 0.f);
    int b0 = rp0[node], e0 = rp0[node + 1];
    for (int e = b0; e < e0; ++e) {
        int s = csr0[e];
        float2 v = *reinterpret_cast<const float2*>(&x[(size_t)s * DD + c]);
        a0.x += v.x;
        a0.y += v.y;
    }
    int b1 = rp1[node], e1 = rp1[node + 1];
    for (int e = b1; e < e1; ++e) {
        int s = csr1[e];
        float2 v = *reinterpret_cast<const float2*>(&x[(size_t)s * DD + c]);
        a1.x += v.x;
        a1.y += v.y;
    }
    float r0 = rdeg0[node], r1 = rdeg1[node];
    float2 g;
    g.x = a0.x * r0 + a1.x * r1;
    g.y = a0.y * r0 + a1.y * r1;
    *reinterpret_cast<float2*>(&gt[(size_t)node * DD + c]) = g;
}

// ---------------- fused dual GEMM + bias (+ReLU) ----------------
// out[n,d] = 2*x[n,:]@Ws[:,d] + gt[n,:]@Wn[:,d] + 2*b[d]
__global__ __launch_bounds__(256) void gemm_kernel(const float* __restrict__ x,
                                                   const float* __restrict__ gt_in,
                                                   const float* __restrict__ Ws,
                                                   const float* __restrict__ Wn,
                                                   const float* __restrict__ b,
                                                   float* __restrict__ out,
                                                   int relu) {
    __shared__ float x2t[8][DD];  // 2*x rows
    __shared__ float gt[8][DD];   // combined mean rows
    const int tid  = threadIdx.x;
    const int row0 = blockIdx.x * 8;

    {
        int r  = tid >> 5;
        int c4 = (tid & 31) << 2;
        int n  = row0 + r;
        float4 xv = *reinterpret_cast<const float4*>(&x[(size_t)n * DD + c4]);
        float4 gv = *reinterpret_cast<const float4*>(&gt_in[(size_t)n * DD + c4]);
        x2t[r][c4 + 0] = 2.0f * xv.x;
        x2t[r][c4 + 1] = 2.0f * xv.y;
        x2t[r][c4 + 2] = 2.0f * xv.z;
        x2t[r][c4 + 3] = 2.0f * xv.w;
        gt[r][c4 + 0] = gv.x;
        gt[r][c4 + 1] = gv.y;
        gt[r][c4 + 2] = gv.z;
        gt[r][c4 + 3] = gv.w;
    }
    __syncthreads();

    const int d  = tid & 127;
    const int rg = tid >> 7;  // 0..1
    float acc[4] = {0.f, 0.f, 0.f, 0.f};

    for (int k = 0; k < DD; k += 4) {
        float ws[4], wn[4];
#pragma unroll
        for (int kk = 0; kk < 4; ++kk) {
            ws[kk] = Ws[(size_t)(k + kk) * DD + d];
            wn[kk] = Wn[(size_t)(k + kk) * DD + d];
        }
#pragma unroll
        for (int i = 0; i < 4; ++i) {
            const float4 xv = *reinterpret_cast<const float4*>(&x2t[rg * 4 + i][k]);
            const float4 gv = *reinterpret_cast<const float4*>(&gt[rg * 4 + i][k]);
            acc[i] = fmaf(xv.x, ws[0], acc[i]);
            acc[i] = fmaf(xv.y, ws[1], acc[i]);
            acc[i] = fmaf(xv.z, ws[2], acc[i]);
            acc[i] = fmaf(xv.w, ws[3], acc[i]);
            acc[i] = fmaf(gv.x, wn[0], acc[i]);
            acc[i] = fmaf(gv.y, wn[1], acc[i]);
            acc[i] = fmaf(gv.z, wn[2], acc[i]);
            acc[i] = fmaf(gv.w, wn[3], acc[i]);
        }
    }

    const float bb = 2.0f * b[d];
#pragma unroll
    for (int i = 0; i < 4; ++i) {
        int n   = row0 + rg * 4 + i;
        float v = acc[i] + bb;
        if (relu) v = fmaxf(v, 0.0f);
        out[(size_t)n * DD + d] = v;
    }
}

extern "C" void kernel_launch(void* const* d_in, const int* in_sizes, int n_in,
                              void* d_out, int out_size, void* d_ws, size_t ws_size,
                              hipStream_t stream) {
    (void)in_sizes; (void)n_in; (void)out_size; (void)ws_size;

    const float* h    = (const float*)d_in[0];
    const int*   src0 = (const int*)d_in[1];
    const int*   dst0 = (const int*)d_in[2];
    const int*   src1 = (const int*)d_in[3];
    const int*   dst1 = (const int*)d_in[4];
    const float* Ws1  = (const float*)d_in[5];
    const float* Wn1  = (const float*)d_in[6];
    const float* b1   = (const float*)d_in[7];
    const float* Ws2  = (const float*)d_in[8];
    const float* Wn2  = (const float*)d_in[9];
    const float* b2   = (const float*)d_in[10];
    float* out = (float*)d_out;

    const size_t ND = (size_t)NN * DD;
    // float region
    float* gt    = (float*)d_ws;      // ND
    float* h1    = gt + ND;           // ND
    float* rdeg0 = h1 + ND;           // NN
    float* rdeg1 = rdeg0 + NN;        // NN
    // int region
    int* deg0 = (int*)(rdeg1 + NN);   // NN
    int* deg1 = deg0 + NN;            // NN
    int* cur0 = deg1 + NN;            // NN
    int* cur1 = cur0 + NN;            // NN
    int* rp0  = cur1 + NN;            // NN+1
    int* rp1  = rp0 + NN + 1;         // NN+1
    int* csr0 = rp1 + NN + 1;         // EE
    int* csr1 = csr0 + EE;            // EE

    const int eBlocks    = (EE + 255) / 256;   // 1954
    const int nBlocks    = (NN + 255) / 256;   // 196
    const int aggBlocks  = NN / 4;             // 12500 exact
    const int gemmBlocks = NN / 8;             // 6250 exact

    // ---- CSR build (graph is layer-invariant; built once, used 4x) ----
    hipMemsetAsync(deg0, 0, 4 * (size_t)NN * sizeof(int), stream);  // deg0,deg1,cur0,cur1
    degi_kernel<<<eBlocks, 256, 0, stream>>>(dst0, dst1, deg0, deg1);
    scan_kernel<<<2, 1024, 0, stream>>>(deg0, deg1, rp0, rp1);
    rdegi_kernel<<<nBlocks, 256, 0, stream>>>(deg0, deg1, rdeg0, rdeg1);
    fill_kernel<<<eBlocks, 256, 0, stream>>>(src0, dst0, src1, dst1,
                                             rp0, cur0, csr0, rp1, cur1, csr1);

    // ---- layer 1 ----
    agg_gather_kernel<<<aggBlocks, 256, 0, stream>>>(h, rp0, csr0, rp1, csr1,
                                                     rdeg0, rdeg1, gt);
    gemm_kernel<<<gemmBlocks, 256, 0, stream>>>(h, gt, Ws1, Wn1, b1, h1, 1);

    // ---- layer 2 ----
    agg_gather_kernel<<<aggBlocks, 256, 0, stream>>>(h1, rp0, csr0, rp1, csr1,
                                                     rdeg0, rdeg1, gt);
    gemm_kernel<<<gemmBlocks, 256, 0, stream>>>(h1, gt, Ws2, Wn2, b2, out, 0);
}

// Round 10
// 495.678 us; speedup vs baseline: 7.4604x; 1.1363x over previous
//
#include <hip/hip_runtime.h>

#define NN 50000
#define DD 128
#define EE 500000

typedef __attribute__((ext_vector_type(8))) unsigned short ushort8;

static __device__ __forceinline__ unsigned short f2bf(float f) {
    unsigned int u = __float_as_uint(f);
    unsigned int r = (u + 0x7fffu + ((u >> 16) & 1u)) >> 16;
    return (unsigned short)r;
}
static __device__ __forceinline__ float bf2f(unsigned short s) {
    return __uint_as_float(((unsigned int)s) << 16);
}

// ---------------- fp32 -> bf16 conversion (8 elems/thread) ----------------
__global__ __launch_bounds__(256) void cvt_kernel(const float* __restrict__ h,
                                                  unsigned short* __restrict__ hb) {
    size_t i = ((size_t)blockIdx.x * 256 + threadIdx.x) * 8;
    float4 a = *reinterpret_cast<const float4*>(&h[i]);
    float4 b = *reinterpret_cast<const float4*>(&h[i + 4]);
    ushort8 o;
    o[0] = f2bf(a.x); o[1] = f2bf(a.y); o[2] = f2bf(a.z); o[3] = f2bf(a.w);
    o[4] = f2bf(b.x); o[5] = f2bf(b.y); o[6] = f2bf(b.z); o[7] = f2bf(b.w);
    *reinterpret_cast<ushort8*>(&hb[i]) = o;
}

// ---------------- int degree histogram (both edge types) ----------------
__global__ __launch_bounds__(256) void degi_kernel(const int* __restrict__ dst0,
                                                   const int* __restrict__ dst1,
                                                   int* __restrict__ deg0,
                                                   int* __restrict__ deg1) {
    int i = blockIdx.x * 256 + threadIdx.x;
    if (i < EE) {
        atomicAdd(&deg0[dst0[i]], 1);
        atomicAdd(&deg1[dst1[i]], 1);
    }
}

// ---------------- exclusive scan deg -> row_ptr (one block per edge type) ----------------
__global__ __launch_bounds__(1024) void scan_kernel(const int* __restrict__ deg0,
                                                    const int* __restrict__ deg1,
                                                    int* __restrict__ rp0,
                                                    int* __restrict__ rp1) {
    const int* deg = blockIdx.x ? deg1 : deg0;
    int* rp = blockIdx.x ? rp1 : rp0;
    __shared__ int spart[1024];
    int running = 0;
    for (int base = 0; base < NN; base += 8192) {
        int i0 = base + threadIdx.x * 8;
        int v[8];
        int local = 0;
#pragma unroll
        for (int j = 0; j < 8; ++j) {
            int idx = i0 + j;
            v[j] = (idx < NN) ? deg[idx] : 0;
            local += v[j];
        }
        spart[threadIdx.x] = local;
        __syncthreads();
        for (int off = 1; off < 1024; off <<= 1) {
            int t = (threadIdx.x >= off) ? spart[threadIdx.x - off] : 0;
            __syncthreads();
            spart[threadIdx.x] += t;
            __syncthreads();
        }
        int excl = running + spart[threadIdx.x] - local;
        int total = spart[1023];
#pragma unroll
        for (int j = 0; j < 8; ++j) {
            int idx = i0 + j;
            if (idx < NN) rp[idx] = excl;
            excl += v[j];
        }
        running += total;
        __syncthreads();
    }
    if (threadIdx.x == 0) rp[NN] = running;
}

// ---------------- rdeg = 1/max(deg,1) ----------------
__global__ __launch_bounds__(256) void rdegi_kernel(const int* __restrict__ deg0,
                                                    const int* __restrict__ deg1,
                                                    float* __restrict__ rdeg0,
                                                    float* __restrict__ rdeg1) {
    int i = blockIdx.x * 256 + threadIdx.x;
    if (i < NN) {
        rdeg0[i] = 1.0f / fmaxf((float)deg0[i], 1.0f);
        rdeg1[i] = 1.0f / fmaxf((float)deg1[i], 1.0f);
    }
}

// ---------------- scatter edges into CSR (both edge types) ----------------
__global__ __launch_bounds__(256) void fill_kernel(const int* __restrict__ src0,
                                                   const int* __restrict__ dst0,
                                                   const int* __restrict__ src1,
                                                   const int* __restrict__ dst1,
                                                   const int* __restrict__ rp0,
                                                   int* __restrict__ cur0,
                                                   int* __restrict__ csr0,
                                                   const int* __restrict__ rp1,
                                                   int* __restrict__ cur1,
                                                   int* __restrict__ csr1) {
    int e = blockIdx.x * 256 + threadIdx.x;
    if (e < EE) {
        int d0 = dst0[e];
        int p0 = atomicAdd(&cur0[d0], 1);
        csr0[rp0[d0] + p0] = src0[e];
        int d1 = dst1[e];
        int p1 = atomicAdd(&cur1[d1], 1);
        csr1[rp1[d1] + p1] = src1[e];
    }
}

// ---------------- gather aggregation (bf16 rows, 4 neighbors in flight/wave) ----------------
// one wave per node; lane = sub(2b) x lc(4b): sub = neighbor slot, lc = col-chunk of 8 bf16 (16B)
__global__ __launch_bounds__(256) void agg_gather_kernel(const unsigned short* __restrict__ xb,
                                                         const int* __restrict__ rp0,
                                                         const int* __restrict__ csr0,
                                                         const int* __restrict__ rp1,
                                                         const int* __restrict__ csr1,
                                                         const float* __restrict__ rdeg0,
                                                         const float* __restrict__ rdeg1,
                                                         float* __restrict__ gt) {
    int tid  = threadIdx.x;
    int node = blockIdx.x * 4 + (tid >> 6);
    int lane = tid & 63;
    int sub  = lane >> 4;   // 0..3 : which neighbor within a 4-group
    int lc   = lane & 15;   // col chunk: cols lc*8 .. lc*8+7

    float a0[8] = {0.f, 0.f, 0.f, 0.f, 0.f, 0.f, 0.f, 0.f};
    float a1[8] = {0.f, 0.f, 0.f, 0.f, 0.f, 0.f, 0.f, 0.f};

    int b0 = rp0[node], e0 = rp0[node + 1];
    for (int e = b0 + sub; e < e0; e += 4) {
        int s = csr0[e];
        ushort8 v = *reinterpret_cast<const ushort8*>(&xb[(size_t)s * DD + lc * 8]);
#pragma unroll
        for (int j = 0; j < 8; ++j) a0[j] += bf2f(v[j]);
    }
    int b1 = rp1[node], e1 = rp1[node + 1];
    for (int e = b1 + sub; e < e1; e += 4) {
        int s = csr1[e];
        ushort8 v = *reinterpret_cast<const ushort8*>(&xb[(size_t)s * DD + lc * 8]);
#pragma unroll
        for (int j = 0; j < 8; ++j) a1[j] += bf2f(v[j]);
    }

    float r0 = rdeg0[node], r1 = rdeg1[node];
    float g[8];
#pragma unroll
    for (int j = 0; j < 8; ++j) {
        g[j] = a0[j] * r0 + a1[j] * r1;
        g[j] += __shfl_xor(g[j], 16);
        g[j] += __shfl_xor(g[j], 32);
    }
    if (sub == 0) {
        float4 lo = make_float4(g[0], g[1], g[2], g[3]);
        float4 hi = make_float4(g[4], g[5], g[6], g[7]);
        *reinterpret_cast<float4*>(&gt[(size_t)node * DD + lc * 8])     = lo;
        *reinterpret_cast<float4*>(&gt[(size_t)node * DD + lc * 8 + 4]) = hi;
    }
}

// ---------------- fused dual GEMM + bias (+ReLU) ----------------
// out[n,d] = 2*x[n,:]@Ws[:,d] + gt[n,:]@Wn[:,d] + 2*b[d]
// 16 rows/block, 256 threads = 32 col-groups(4 cols) x 8 row-groups(2 rows)
// LDS bytes/FMA = 1 (each float4 read feeds 4k x 4cols FMAs via regs)
__global__ __launch_bounds__(256) void gemm_kernel(const unsigned short* __restrict__ xb,
                                                   const float* __restrict__ gt_in,
                                                   const float* __restrict__ Ws,
                                                   const float* __restrict__ Wn,
                                                   const float* __restrict__ b,
                                                   float* __restrict__ outf,
                                                   unsigned short* __restrict__ outb,
                                                   int relu) {
    __shared__ float x2t[16][DD];  // 2*x rows (from bf16)
    __shared__ float gtt[16][DD];  // combined mean rows
    const int tid  = threadIdx.x;
    const int row0 = blockIdx.x * 16;

    {
        int r  = tid >> 4;        // 0..15
        int c8 = (tid & 15) * 8;  // 0..120
        size_t base = (size_t)(row0 + r) * DD + c8;
        ushort8 xv = *reinterpret_cast<const ushort8*>(&xb[base]);
        float4 g0 = *reinterpret_cast<const float4*>(&gt_in[base]);
        float4 g1 = *reinterpret_cast<const float4*>(&gt_in[base + 4]);
#pragma unroll
        for (int j = 0; j < 8; ++j) x2t[r][c8 + j] = 2.0f * bf2f(xv[j]);
        *reinterpret_cast<float4*>(&gtt[r][c8])     = g0;
        *reinterpret_cast<float4*>(&gtt[r][c8 + 4]) = g1;
    }
    __syncthreads();

    const int cg = tid & 31;   // col group -> cols d0..d0+3
    const int rg = tid >> 5;   // 0..7 -> rows rg*2, rg*2+1
    const int d0 = cg * 4;

    float acc[2][4];
#pragma unroll
    for (int i = 0; i < 2; ++i)
#pragma unroll
        for (int c = 0; c < 4; ++c) acc[i][c] = 0.f;

    for (int k = 0; k < DD; k += 4) {
        float4 ws[4], wn[4];
#pragma unroll
        for (int kk = 0; kk < 4; ++kk) {
            ws[kk] = *reinterpret_cast<const float4*>(&Ws[(size_t)(k + kk) * DD + d0]);
            wn[kk] = *reinterpret_cast<const float4*>(&Wn[(size_t)(k + kk) * DD + d0]);
        }
#pragma unroll
        for (int i = 0; i < 2; ++i) {
            int r = rg * 2 + i;
            float4 xv = *reinterpret_cast<const float4*>(&x2t[r][k]);
            float4 gv = *reinterpret_cast<const float4*>(&gtt[r][k]);
            const float xk[4] = {xv.x, xv.y, xv.z, xv.w};
            const float gk[4] = {gv.x, gv.y, gv.z, gv.w};
#pragma unroll
            for (int kk = 0; kk < 4; ++kk) {
                const float* wsp = &ws[kk].x;
                const float* wnp = &wn[kk].x;
#pragma unroll
                for (int c = 0; c < 4; ++c) {
                    acc[i][c] = fmaf(xk[kk], wsp[c], acc[i][c]);
                    acc[i][c] = fmaf(gk[kk], wnp[c], acc[i][c]);
                }
            }
        }
    }

#pragma unroll
    for (int i = 0; i < 2; ++i) {
        int n = row0 + rg * 2 + i;
        float v[4];
#pragma unroll
        for (int c = 0; c < 4; ++c) {
            v[c] = acc[i][c] + 2.0f * b[d0 + c];
            if (relu) v[c] = fmaxf(v[c], 0.0f);
        }
        if (outf) {
            *reinterpret_cast<float4*>(&outf[(size_t)n * DD + d0]) =
                make_float4(v[0], v[1], v[2], v[3]);
        }
        if (outb) {
            ushort4 o;
            o.x = f2bf(v[0]); o.y = f2bf(v[1]); o.z = f2bf(v[2]); o.w = f2bf(v[3]);
            *reinterpret_cast<ushort4*>(&outb[(size_t)n * DD + d0]) = o;
        }
    }
}

extern "C" void kernel_launch(void* const* d_in, const int* in_sizes, int n_in,
                              void* d_out, int out_size, void* d_ws, size_t ws_size,
                              hipStream_t stream) {
    (void)in_sizes; (void)n_in; (void)out_size; (void)ws_size;

    const float* h    = (const float*)d_in[0];
    const int*   src0 = (const int*)d_in[1];
    const int*   dst0 = (const int*)d_in[2];
    const int*   src1 = (const int*)d_in[3];
    const int*   dst1 = (const int*)d_in[4];
    const float* Ws1  = (const float*)d_in[5];
    const float* Wn1  = (const float*)d_in[6];
    const float* b1   = (const float*)d_in[7];
    const float* Ws2  = (const float*)d_in[8];
    const float* Wn2  = (const float*)d_in[9];
    const float* b2   = (const float*)d_in[10];
    float* out = (float*)d_out;

    const size_t ND = (size_t)NN * DD;
    // float region
    float* gt    = (float*)d_ws;              // ND f32
    float* rdeg0 = gt + ND;                   // NN
    float* rdeg1 = rdeg0 + NN;                // NN
    // bf16 region
    unsigned short* hb  = (unsigned short*)(rdeg1 + NN);  // ND ushort
    unsigned short* h1b = hb + ND;                        // ND ushort
    // int region
    int* deg0 = (int*)(h1b + ND);             // NN
    int* deg1 = deg0 + NN;                    // NN
    int* cur0 = deg1 + NN;                    // NN
    int* cur1 = cur0 + NN;                    // NN
    int* rp0  = cur1 + NN;                    // NN+1
    int* rp1  = rp0 + NN + 1;                 // NN+1
    int* csr0 = rp1 + NN + 1;                 // EE
    int* csr1 = csr0 + EE;                    // EE

    const int eBlocks    = (EE + 255) / 256;   // 1954
    const int nBlocks    = (NN + 255) / 256;   // 196
    const int cvtBlocks  = (int)(ND / (256 * 8));  // 3125 exact
    const int aggBlocks  = NN / 4;             // 12500 exact
    const int gemmBlocks = NN / 16;            // 3125 exact

    // ---- CSR build + bf16 convert (graph is layer-invariant; built once, used 4x) ----
    hipMemsetAsync(deg0, 0, 4 * (size_t)NN * sizeof(int), stream);  // deg0,deg1,cur0,cur1
    cvt_kernel<<<cvtBlocks, 256, 0, stream>>>(h, hb);
    degi_kernel<<<eBlocks, 256, 0, stream>>>(dst0, dst1, deg0, deg1);
    scan_kernel<<<2, 1024, 0, stream>>>(deg0, deg1, rp0, rp1);
    rdegi_kernel<<<nBlocks, 256, 0, stream>>>(deg0, deg1, rdeg0, rdeg1);
    fill_kernel<<<eBlocks, 256, 0, stream>>>(src0, dst0, src1, dst1,
                                             rp0, cur0, csr0, rp1, cur1, csr1);

    // ---- layer 1 (h in bf16; out h1 in bf16) ----
    agg_gather_kernel<<<aggBlocks, 256, 0, stream>>>(hb, rp0, csr0, rp1, csr1,
                                                     rdeg0, rdeg1, gt);
    gemm_kernel<<<gemmBlocks, 256, 0, stream>>>(hb, gt, Ws1, Wn1, b1,
                                                nullptr, h1b, 1);

    // ---- layer 2 (h1 in bf16; out fp32) ----
    agg_gather_kernel<<<aggBlocks, 256, 0, stream>>>(h1b, rp0, csr0, rp1, csr1,
                                                     rdeg0, rdeg1, gt);
    gemm_kernel<<<gemmBlocks, 256, 0, stream>>>(h1b, gt, Ws2, Wn2, b2,
                                                out, nullptr, 0);
}

// Round 13
// 377.726 us; speedup vs baseline: 9.7901x; 1.3123x over previous
//
#include <hip/hip_runtime.h>

#define NN 50000
#define DD 128
#define EE 500000

typedef __attribute__((ext_vector_type(8))) unsigned short ushort8;
typedef __attribute__((ext_vector_type(8))) short bf16x8v;   // 8 bf16 in 4 VGPRs
typedef __attribute__((ext_vector_type(4))) float f32x4;

static __device__ __forceinline__ unsigned short f2bf(float f) {
    unsigned int u = __float_as_uint(f);
    unsigned int r = (u + 0x7fffu + ((u >> 16) & 1u)) >> 16;
    return (unsigned short)r;
}
static __device__ __forceinline__ float bf2f(unsigned short s) {
    return __uint_as_float(((unsigned int)s) << 16);
}

// ---------------- A1 self half: A1[m][0..127] = bf16(2*h[m][d]) ----------------
__global__ __launch_bounds__(256) void cvt_kernel(const float* __restrict__ h,
                                                  unsigned short* __restrict__ A1) {
    size_t i = ((size_t)blockIdx.x * 256 + threadIdx.x) * 8;  // over ND = NN*128
    int m = (int)(i >> 7);
    int d = (int)(i & 127);
    float4 a = *reinterpret_cast<const float4*>(&h[i]);
    float4 b = *reinterpret_cast<const float4*>(&h[i + 4]);
    ushort8 o;
    o[0] = f2bf(2.f * a.x); o[1] = f2bf(2.f * a.y); o[2] = f2bf(2.f * a.z); o[3] = f2bf(2.f * a.w);
    o[4] = f2bf(2.f * b.x); o[5] = f2bf(2.f * b.y); o[6] = f2bf(2.f * b.z); o[7] = f2bf(2.f * b.w);
    *reinterpret_cast<ushort8*>(&A1[(size_t)m * 256 + d]) = o;
}

// ---------------- weights: Bt[n][k] bf16, k in [0,256) = [Ws ; Wn] ----------------
__global__ __launch_bounds__(256) void wprep_kernel(const float* __restrict__ Ws1,
                                                    const float* __restrict__ Wn1,
                                                    const float* __restrict__ Ws2,
                                                    const float* __restrict__ Wn2,
                                                    unsigned short* __restrict__ Bt1,
                                                    unsigned short* __restrict__ Bt2) {
    int t = blockIdx.x * 256 + threadIdx.x;  // 0..65535
    int lay = t >> 15;
    int r = t & 32767;
    int k = r >> 7;    // 0..255
    int n = r & 127;
    const float* Ws = lay ? Ws2 : Ws1;
    const float* Wn = lay ? Wn2 : Wn1;
    unsigned short* Bt = lay ? Bt2 : Bt1;
    float v = (k < 128) ? Ws[(size_t)k * 128 + n] : Wn[(size_t)(k - 128) * 128 + n];
    Bt[(size_t)n * 256 + k] = f2bf(v);
}

// ---------------- int degree histogram (both edge types) ----------------
__global__ __launch_bounds__(256) void degi_kernel(const int* __restrict__ dst0,
                                                   const int* __restrict__ dst1,
                                                   int* __restrict__ deg0,
                                                   int* __restrict__ deg1) {
    int i = blockIdx.x * 256 + threadIdx.x;
    if (i < EE) {
        atomicAdd(&deg0[dst0[i]], 1);
        atomicAdd(&deg1[dst1[i]], 1);
    }
}

// ---------------- exclusive scan deg -> row_ptr (one block per edge type) ----------------
__global__ __launch_bounds__(1024) void scan_kernel(const int* __restrict__ deg0,
                                                    const int* __restrict__ deg1,
                                                    int* __restrict__ rp0,
                                                    int* __restrict__ rp1) {
    const int* deg = blockIdx.x ? deg1 : deg0;
    int* rp = blockIdx.x ? rp1 : rp0;
    __shared__ int spart[1024];
    int running = 0;
    for (int base = 0; base < NN; base += 8192) {
        int i0 = base + threadIdx.x * 8;
        int v[8];
        int local = 0;
#pragma unroll
        for (int j = 0; j < 8; ++j) {
            int idx = i0 + j;
            v[j] = (idx < NN) ? deg[idx] : 0;
            local += v[j];
        }
        spart[threadIdx.x] = local;
        __syncthreads();
        for (int off = 1; off < 1024; off <<= 1) {
            int t = (threadIdx.x >= off) ? spart[threadIdx.x - off] : 0;
            __syncthreads();
            spart[threadIdx.x] += t;
            __syncthreads();
        }
        int excl = running + spart[threadIdx.x] - local;
        int total = spart[1023];
#pragma unroll
        for (int j = 0; j < 8; ++j) {
            int idx = i0 + j;
            if (idx < NN) rp[idx] = excl;
            excl += v[j];
        }
        running += total;
        __syncthreads();
    }
    if (threadIdx.x == 0) rp[NN] = running;
}

// ---------------- rdeg = 1/max(deg,1) ----------------
__global__ __launch_bounds__(256) void rdegi_kernel(const int* __restrict__ deg0,
                                                    const int* __restrict__ deg1,
                                                    float* __restrict__ rdeg0,
                                                    float* __restrict__ rdeg1) {
    int i = blockIdx.x * 256 + threadIdx.x;
    if (i < NN) {
        rdeg0[i] = 1.0f / fmaxf((float)deg0[i], 1.0f);
        rdeg1[i] = 1.0f / fmaxf((float)deg1[i], 1.0f);
    }
}

// ---------------- scatter edges into CSR (both edge types) ----------------
__global__ __launch_bounds__(256) void fill_kernel(const int* __restrict__ src0,
                                                   const int* __restrict__ dst0,
                                                   const int* __restrict__ src1,
                                                   const int* __restrict__ dst1,
                                                   const int* __restrict__ rp0,
                                                   int* __restrict__ cur0,
                                                   int* __restrict__ csr0,
                                                   const int* __restrict__ rp1,
                                                   int* __restrict__ cur1,
                                                   int* __restrict__ csr1) {
    int e = blockIdx.x * 256 + threadIdx.x;
    if (e < EE) {
        int d0 = dst0[e];
        int p0 = atomicAdd(&cur0[d0], 1);
        csr0[rp0[d0] + p0] = src0[e];
        int d1 = dst1[e];
        int p1 = atomicAdd(&cur1[d1], 1);
        csr1[rp1[d1] + p1] = src1[e];
    }
}

// ---------------- gather: A[node][128+c] = bf16( mean0 + mean1 ) ----------------
// reads self half A[s][0..127] (= bf16(2*x[s])); scale folds the 0.5 into rdeg.
// one wave per node; lane = sub(2b) x lc(4b); 4 neighbors in flight per wave.
__global__ __launch_bounds__(256) void agg_gather_kernel(unsigned short* __restrict__ A,
                                                         const int* __restrict__ rp0,
                                                         const int* __restrict__ csr0,
                                                         const int* __restrict__ rp1,
                                                         const int* __restrict__ csr1,
                                                         const float* __restrict__ rdeg0,
                                                         const float* __restrict__ rdeg1) {
    int tid  = threadIdx.x;
    int node = blockIdx.x * 4 + (tid >> 6);
    int lane = tid & 63;
    int sub  = lane >> 4;   // neighbor slot 0..3
    int lc   = lane & 15;   // col chunk of 8 bf16

    float a0[8] = {0.f, 0.f, 0.f, 0.f, 0.f, 0.f, 0.f, 0.f};
    float a1[8] = {0.f, 0.f, 0.f, 0.f, 0.f, 0.f, 0.f, 0.f};

    int b0 = rp0[node], e0 = rp0[node + 1];
    for (int e = b0 + sub; e < e0; e += 4) {
        int s = csr0[e];
        ushort8 v = *reinterpret_cast<const ushort8*>(&A[(size_t)s * 256 + lc * 8]);
#pragma unroll
        for (int j = 0; j < 8; ++j) a0[j] += bf2f(v[j]);
    }
    int b1 = rp1[node], e1 = rp1[node + 1];
    for (int e = b1 + sub; e < e1; e += 4) {
        int s = csr1[e];
        ushort8 v = *reinterpret_cast<const ushort8*>(&A[(size_t)s * 256 + lc * 8]);
#pragma unroll
        for (int j = 0; j < 8; ++j) a1[j] += bf2f(v[j]);
    }

    float r0 = 0.5f * rdeg0[node], r1 = 0.5f * rdeg1[node];
    float g[8];
#pragma unroll
    for (int j = 0; j < 8; ++j) {
        g[j] = a0[j] * r0 + a1[j] * r1;
        g[j] += __shfl_xor(g[j], 16);
        g[j] += __shfl_xor(g[j], 32);
    }
    if (sub == 0) {
        ushort8 o;
#pragma unroll
        for (int j = 0; j < 8; ++j) o[j] = f2bf(g[j]);
        *reinterpret_cast<ushort8*>(&A[(size_t)node * 256 + 128 + lc * 8]) = o;
    }
}

// ---------------- MFMA GEMM: out[m][n] = A[m][0..255] @ Bt[n][0..255] + 2*b[n] ----------------
// 64 rows/block, 4 waves x 16 rows; per wave: 8 col-frags x 8 k-steps of mfma_f32_16x16x32_bf16.
// A frag: row = lane&15, k = 32*ks + 8*(lane>>4)+j (row-major ushort8).
// B frag: col = lane&15, same k (contiguous because Bt is n-major = B^T).
// C/D: col = lane&15, row = 4*(lane>>4)+reg  [m89-verified].
__global__ __launch_bounds__(256) void mfma_gemm_kernel(const unsigned short* __restrict__ A,
                                                        const unsigned short* __restrict__ Bt,
                                                        const float* __restrict__ bias,
                                                        float* __restrict__ outf,
                                                        unsigned short* __restrict__ a2self,
                                                        int relu) {
    const int tid  = threadIdx.x;
    const int wave = tid >> 6;
    const int lane = tid & 63;
    const int lr   = lane & 15;
    const int lk   = (lane >> 4) * 8;
    const int rowbase = blockIdx.x * 64 + wave * 16;

    int arow = rowbase + lr;
    if (arow >= NN) arow = NN - 1;  // clamp (stores are guarded)
    const unsigned short* Ap = A + (size_t)arow * 256 + lk;
    const unsigned short* Bp = Bt + (size_t)lr * 256 + lk;

    f32x4 acc[8];
#pragma unroll
    for (int cf = 0; cf < 8; ++cf) acc[cf] = (f32x4){0.f, 0.f, 0.f, 0.f};

    for (int ks = 0; ks < 8; ++ks) {
        bf16x8v a = *reinterpret_cast<const bf16x8v*>(Ap + ks * 32);
#pragma unroll
        for (int cf = 0; cf < 8; ++cf) {
            bf16x8v b = *reinterpret_cast<const bf16x8v*>(Bp + cf * (16 * 256) + ks * 32);
            acc[cf] = __builtin_amdgcn_mfma_f32_16x16x32_bf16(a, b, acc[cf], 0, 0, 0);
        }
    }

    const int rfrag = (lane >> 4) * 4;
#pragma unroll
    for (int cf = 0; cf < 8; ++cf) {
        int col = cf * 16 + lr;
        float bb = 2.0f * bias[col];
#pragma unroll
        for (int rg = 0; rg < 4; ++rg) {
            int r = rowbase + rfrag + rg;
            if (r < NN) {
                float v = acc[cf][rg] + bb;
                if (relu) v = fmaxf(v, 0.f);
                if (outf) {
                    outf[(size_t)r * 128 + col] = v;
                } else {
                    a2self[(size_t)r * 256 + col] = f2bf(2.0f * v);
                }
            }
        }
    }
}

extern "C" void kernel_launch(void* const* d_in, const int* in_sizes, int n_in,
                              void* d_out, int out_size, void* d_ws, size_t ws_size,
                              hipStream_t stream) {
    (void)in_sizes; (void)n_in; (void)out_size; (void)ws_size;

    const float* h    = (const float*)d_in[0];
    const int*   src0 = (const int*)d_in[1];
    const int*   dst0 = (const int*)d_in[2];
    const int*   src1 = (const int*)d_in[3];
    const int*   dst1 = (const int*)d_in[4];
    const float* Ws1  = (const float*)d_in[5];
    const float* Wn1  = (const float*)d_in[6];
    const float* b1   = (const float*)d_in[7];
    const float* Ws2  = (const float*)d_in[8];
    const float* Wn2  = (const float*)d_in[9];
    const float* b2   = (const float*)d_in[10];
    float* out = (float*)d_out;

    const size_t ND  = (size_t)NN * DD;   // 6.4M
    const size_t ND2 = (size_t)NN * 256;  // 12.8M

    unsigned short* A1  = (unsigned short*)d_ws;  // ND2
    unsigned short* A2  = A1 + ND2;               // ND2
    unsigned short* Bt1 = A2 + ND2;               // 32768
    unsigned short* Bt2 = Bt1 + 32768;            // 32768
    float* rdeg0 = (float*)(Bt2 + 32768);         // NN
    float* rdeg1 = rdeg0 + NN;                    // NN
    int* deg0 = (int*)(rdeg1 + NN);               // NN
    int* deg1 = deg0 + NN;                        // NN
    int* cur0 = deg1 + NN;                        // NN
    int* cur1 = cur0 + NN;                        // NN
    int* rp0  = cur1 + NN;                        // NN+1
    int* rp1  = rp0 + NN + 1;                     // NN+1
    int* csr0 = rp1 + NN + 1;                     // EE
    int* csr1 = csr0 + EE;                        // EE

    const int eBlocks    = (EE + 255) / 256;       // 1954
    const int nBlocks    = (NN + 255) / 256;       // 196
    const int cvtBlocks  = (int)(ND / (256 * 8));  // 3125 exact
    const int aggBlocks  = NN / 4;                 // 12500 exact
    const int gemmBlocks = (NN + 63) / 64;         // 782

    // ---- prep: bf16 A1 self, bf16 transposed weights, CSR build ----
    hipMemsetAsync(deg0, 0, 4 * (size_t)NN * sizeof(int), stream);  // deg0,deg1,cur0,cur1
    cvt_kernel<<<cvtBlocks, 256, 0, stream>>>(h, A1);
    wprep_kernel<<<256, 256, 0, stream>>>(Ws1, Wn1, Ws2, Wn2, Bt1, Bt2);
    degi_kernel<<<eBlocks, 256, 0, stream>>>(dst0, dst1, deg0, deg1);
    scan_kernel<<<2, 1024, 0, stream>>>(deg0, deg1, rp0, rp1);
    rdegi_kernel<<<nBlocks, 256, 0, stream>>>(deg0, deg1, rdeg0, rdeg1);
    fill_kernel<<<eBlocks, 256, 0, stream>>>(src0, dst0, src1, dst1,
                                             rp0, cur0, csr0, rp1, cur1, csr1);

    // ---- layer 1 ----
    agg_gather_kernel<<<aggBlocks, 256, 0, stream>>>(A1, rp0, csr0, rp1, csr1, rdeg0, rdeg1);
    mfma_gemm_kernel<<<gemmBlocks, 256, 0, stream>>>(A1, Bt1, b1, nullptr, A2, 1);

    // ---- layer 2 ----
    agg_gather_kernel<<<aggBlocks, 256, 0, stream>>>(A2, rp0, csr0, rp1, csr1, rdeg0, rdeg1);
    mfma_gemm_kernel<<<gemmBlocks, 256, 0, stream>>>(A2, Bt2, b2, out, nullptr, 0);
}